// Round 1
// baseline (591.841 us; speedup 1.0000x reference)
//
#include <hip/hip_runtime.h>
#include <stdint.h>

typedef __attribute__((ext_vector_type(8))) short short8;
typedef __attribute__((ext_vector_type(4))) float floatx4;

__device__ inline unsigned short f2bf(float f) {
    unsigned int u = __float_as_uint(f);
    u += 0x7fffu + ((u >> 16) & 1u);   // round-to-nearest-even
    return (unsigned short)(u >> 16);
}

// ---------------------------------------------------------------------------
// Average over E experts + transpose + fp32->bf16.  src[e, k, n] (row-major),
// dst[n, k] bf16 with leading dim ldb.  Rows n in [Nsrc, Ndst) are zero-filled
// (used to pad rw2 from N=100 to 128).
// ---------------------------------------------------------------------------
__global__ void avg_transpose_bf16(const float* __restrict__ src,
                                   unsigned short* __restrict__ dst,
                                   int E, int K, int Nsrc, int Ndst, int ldb,
                                   float scale) {
    __shared__ float tile[32][33];
    const int tx = threadIdx.x;   // 0..31
    const int ty = threadIdx.y;   // 0..7
    const int kb = blockIdx.x * 32;
    const int nb = blockIdx.y * 32;
#pragma unroll
    for (int p = 0; p < 4; ++p) {
        int kl = ty + p * 8;
        int k = kb + kl;
        int n = nb + tx;
        float s = 0.f;
        if (k < K && n < Nsrc) {
            for (int e = 0; e < E; ++e)
                s += src[(size_t)e * K * Nsrc + (size_t)k * Nsrc + n];
        }
        tile[kl][tx] = s * scale;
    }
    __syncthreads();
#pragma unroll
    for (int p = 0; p < 4; ++p) {
        int nl = ty + p * 8;
        int n = nb + nl;
        int k = kb + tx;
        if (n < Ndst && k < K)
            dst[(size_t)n * ldb + k] = f2bf(tile[tx][nl]);
    }
}

// mean over 7 experts of the three bias vectors (each [7,1536])
__global__ void bias_means(const float* __restrict__ pb0,
                           const float* __restrict__ pb1,
                           const float* __restrict__ pbib,
                           float* __restrict__ bm0, float* __restrict__ bm1,
                           float* __restrict__ bm2) {
    int i = blockIdx.x * blockDim.x + threadIdx.x;
    if (i >= 1536) return;
    float s0 = 0.f, s1 = 0.f, s2 = 0.f;
    for (int e = 0; e < 7; ++e) {
        s0 += pb0[e * 1536 + i];
        s1 += pb1[e * 1536 + i];
        s2 += pbib[e * 1536 + i];
    }
    const float inv = 1.f / 7.f;
    bm0[i] = s0 * inv; bm1[i] = s1 * inv; bm2[i] = s2 * inv;
}

// fp32 -> bf16 pack, vectorized by 4
__global__ void pack_bf16(const float* __restrict__ src,
                          unsigned short* __restrict__ dst, int n4) {
    int i = blockIdx.x * blockDim.x + threadIdx.x;
    if (i >= n4) return;
    float4 v = ((const float4*)src)[i];
    ushort4 o;
    o.x = f2bf(v.x); o.y = f2bf(v.y); o.z = f2bf(v.z); o.w = f2bf(v.w);
    ((ushort4*)dst)[i] = o;
}

// ---------------------------------------------------------------------------
// bf16 MFMA GEMM, m97 structure: 128x128 tile, BK=32, 4 waves (2x2 of 64x64),
// global_load_lds width 16.  A[M,K] bf16 row-major, Bt[Npad,K] bf16 row-major
// (i.e. B transposed).  C fp32 [M, Nreal] with leading dim ldc.
// MODE 0: C = A*B + bias[n]
// MODE 1: C = A*B + w0[m]*bm0[n] + w1[m]*bm1[n] + w2[m]*bm2[n]
// Requires: M % 128 == 0, grid.y*128 rows valid in Bt, K % 32 == 0.
// ---------------------------------------------------------------------------
template <int MODE>
__global__ __launch_bounds__(256) void gemm_bt(
    const unsigned short* __restrict__ A, const unsigned short* __restrict__ Bt,
    float* __restrict__ C, int K, int Nreal, int ldc,
    const float* __restrict__ bias, const float* __restrict__ w0,
    const float* __restrict__ w1, const float* __restrict__ w2,
    const float* __restrict__ bm0, const float* __restrict__ bm1,
    const float* __restrict__ bm2) {
    __shared__ __align__(16) unsigned short As[128 * 32];
    __shared__ __align__(16) unsigned short Bs[128 * 32];
    const int tid = threadIdx.x;
    const int lane = tid & 63;
    const int wv = tid >> 6;
    const int bm_off = blockIdx.x * 128;
    const int bn_off = blockIdx.y * 128;
    const int wm = (wv & 1) * 64;
    const int wn = (wv >> 1) * 64;
    floatx4 acc[4][4];
#pragma unroll
    for (int i = 0; i < 4; ++i)
#pragma unroll
        for (int j = 0; j < 4; ++j) acc[i][j] = (floatx4){0.f, 0.f, 0.f, 0.f};

    const int quad = lane >> 4;
    const int lrow = lane & 15;
    const int srow = lane >> 2;        // staging: row within 16-row chunk
    const int scol = (lane & 3) * 8;   // staging: elem offset (8 bf16 = 16B)

    const unsigned short* Ag = A + (size_t)bm_off * K;
    const unsigned short* Bg = Bt + (size_t)bn_off * K;

    for (int k0 = 0; k0 < K; k0 += 32) {
#pragma unroll
        for (int r = 0; r < 2; ++r) {
            int chunk = r * 4 + wv;  // 0..7 -> 16-row chunk
            {
                const unsigned short* gp =
                    Ag + (size_t)(chunk * 16 + srow) * K + (k0 + scol);
                __builtin_amdgcn_global_load_lds(
                    (const __attribute__((address_space(1))) void*)gp,
                    (__attribute__((address_space(3))) void*)(As + chunk * 512),
                    16, 0, 0);
            }
            {
                const unsigned short* gp =
                    Bg + (size_t)(chunk * 16 + srow) * K + (k0 + scol);
                __builtin_amdgcn_global_load_lds(
                    (const __attribute__((address_space(1))) void*)gp,
                    (__attribute__((address_space(3))) void*)(Bs + chunk * 512),
                    16, 0, 0);
            }
        }
        __syncthreads();
        short8 af[4], bfr[4];
#pragma unroll
        for (int i = 0; i < 4; ++i)
            af[i] = *(const short8*)(As + (wm + i * 16 + lrow) * 32 + quad * 8);
#pragma unroll
        for (int j = 0; j < 4; ++j)
            bfr[j] = *(const short8*)(Bs + (wn + j * 16 + lrow) * 32 + quad * 8);
#pragma unroll
        for (int i = 0; i < 4; ++i)
#pragma unroll
            for (int j = 0; j < 4; ++j)
                acc[i][j] = __builtin_amdgcn_mfma_f32_16x16x32_bf16(
                    af[i], bfr[j], acc[i][j], 0, 0, 0);
        __syncthreads();
    }

#pragma unroll
    for (int i = 0; i < 4; ++i) {
#pragma unroll
        for (int r = 0; r < 4; ++r) {
            int m = bm_off + wm + i * 16 + quad * 4 + r;
            float wb0 = 0.f, wb1 = 0.f, wb2 = 0.f;
            if (MODE == 1) { wb0 = w0[m]; wb1 = w1[m]; wb2 = w2[m]; }
#pragma unroll
            for (int j = 0; j < 4; ++j) {
                int n = bn_off + wn + j * 16 + lrow;
                if (n < Nreal) {
                    float v = acc[i][j][r];
                    if (MODE == 0) v += bias[n];
                    else v += wb0 * bm0[n] + wb1 * bm1[n] + wb2 * bm2[n];
                    C[(size_t)m * ldc + n] = v;
                }
            }
        }
    }
}

// column sums / sumsq over rows (batch dim), atomically accumulated
__global__ void bn_stats(const float* __restrict__ h, int C, int rows_per_block,
                         float* __restrict__ sum, float* __restrict__ sumsq) {
    int row0 = blockIdx.x * rows_per_block;
    for (int c = threadIdx.x; c < C; c += blockDim.x) {
        float s = 0.f, ss = 0.f;
        for (int r = 0; r < rows_per_block; ++r) {
            float v = h[(size_t)(row0 + r) * C + c];
            s += v;
            ss += v * v;
        }
        atomicAdd(&sum[c], s);
        atomicAdd(&sumsq[c], ss);
    }
}

__global__ void bn_final(int C, float invB, const float* __restrict__ sum,
                         const float* __restrict__ sumsq,
                         const float* __restrict__ g, const float* __restrict__ b,
                         float* __restrict__ scale, float* __restrict__ shift) {
    int c = blockIdx.x * blockDim.x + threadIdx.x;
    if (c >= C) return;
    float m = sum[c] * invB;
    float v = sumsq[c] * invB - m * m;
    float sc = g[c] * rsqrtf(v + 1e-5f);
    scale[c] = sc;
    shift[c] = b[c] - m * sc;
}

// h1n = bf16(relu(scale[c]*h + shift[c])), vectorized by 4.  C4 = C/4.
__global__ void bn_relu_pack(const float* __restrict__ h,
                             unsigned short* __restrict__ out,
                             const float* __restrict__ scale,
                             const float* __restrict__ shift, int C4,
                             int total4) {
    int i = blockIdx.x * blockDim.x + threadIdx.x;
    if (i >= total4) return;
    int c4 = (i % C4) * 4;
    float4 v = ((const float4*)h)[i];
    float4 sc = *(const float4*)(scale + c4);
    float4 sh = *(const float4*)(shift + c4);
    ushort4 o;
    o.x = f2bf(fmaxf(v.x * sc.x + sh.x, 0.f));
    o.y = f2bf(fmaxf(v.y * sc.y + sh.y, 0.f));
    o.z = f2bf(fmaxf(v.z * sc.z + sh.z, 0.f));
    o.w = f2bf(fmaxf(v.w * sc.w + sh.w, 0.f));
    ((ushort4*)out)[i] = o;
}

// BN2-apply + tanh + [100x3] GEMM + sigmoid + softmax, one thread per row
__global__ void router_tail(const float* __restrict__ h2,
                            const float* __restrict__ scale,
                            const float* __restrict__ shift,
                            const float* __restrict__ rw3,
                            const float* __restrict__ rb3,
                            float* __restrict__ w0, float* __restrict__ w1,
                            float* __restrict__ w2) {
    int b = blockIdx.x * blockDim.x + threadIdx.x;
    if (b >= 8192) return;
    float l0 = rb3[0], l1 = rb3[1], l2 = rb3[2];
    const float* hr = h2 + (size_t)b * 100;
    for (int k = 0; k < 100; ++k) {
        float t = tanhf(hr[k] * scale[k] + shift[k]);
        l0 += t * rw3[k * 3 + 0];
        l1 += t * rw3[k * 3 + 1];
        l2 += t * rw3[k * 3 + 2];
    }
    l0 = 1.f / (1.f + expf(-l0));
    l1 = 1.f / (1.f + expf(-l1));
    l2 = 1.f / (1.f + expf(-l2));
    float mx = fmaxf(l0, fmaxf(l1, l2));
    float e0 = expf(l0 - mx), e1 = expf(l1 - mx), e2 = expf(l2 - mx);
    float inv = 1.f / (e0 + e1 + e2);
    w0[b] = e0 * inv; w1[b] = e1 * inv; w2[b] = e2 * inv;
}

// X'[b] = [w0[b]*x0[b] | w1[b]*x1[b] | w2[b]*x_ib[b]] as bf16, [8192, 2816]
__global__ void pack_xp(const float* __restrict__ x0, const float* __restrict__ x1,
                        const float* __restrict__ xib, const float* __restrict__ w0,
                        const float* __restrict__ w1, const float* __restrict__ w2,
                        unsigned short* __restrict__ Xp) {
    int i = blockIdx.x * blockDim.x + threadIdx.x;  // 8192*704 vec4 groups
    if (i >= 8192 * 704) return;
    int b = i / 704;
    int g = i % 704;
    const float* src;
    float w;
    int col;
    if (g < 256)      { src = x0 + (size_t)b * 1024 + g * 4;          w = w0[b]; col = g * 4; }
    else if (g < 448) { src = x1 + (size_t)b * 768 + (g - 256) * 4;   w = w1[b]; col = 1024 + (g - 256) * 4; }
    else              { src = xib + (size_t)b * 1024 + (g - 448) * 4; w = w2[b]; col = 1792 + (g - 448) * 4; }
    float4 v = *(const float4*)src;
    ushort4 o;
    o.x = f2bf(v.x * w); o.y = f2bf(v.y * w);
    o.z = f2bf(v.z * w); o.w = f2bf(v.w * w);
    *(ushort4*)(Xp + (size_t)b * 2816 + col) = o;
}

// per-row L2 normalization in place, one wave per row (1536 cols)
__global__ void l2norm_rows(float* __restrict__ out) {
    int wv = threadIdx.x >> 6;
    int lane = threadIdx.x & 63;
    int row = blockIdx.x * 4 + wv;
    float4* rp = (float4*)(out + (size_t)row * 1536);
    float4 v[6];
    float ss = 0.f;
#pragma unroll
    for (int t = 0; t < 6; ++t) {
        v[t] = rp[lane + t * 64];
        ss += v[t].x * v[t].x + v[t].y * v[t].y + v[t].z * v[t].z + v[t].w * v[t].w;
    }
#pragma unroll
    for (int o = 32; o > 0; o >>= 1) ss += __shfl_xor(ss, o);
    float inv = 1.f / fmaxf(sqrtf(ss), 1e-12f);
#pragma unroll
    for (int t = 0; t < 6; ++t) {
        v[t].x *= inv; v[t].y *= inv; v[t].z *= inv; v[t].w *= inv;
        rp[lane + t * 64] = v[t];
    }
}

extern "C" void kernel_launch(void* const* d_in, const int* in_sizes, int n_in,
                              void* d_out, int out_size, void* d_ws,
                              size_t ws_size, hipStream_t stream) {
    (void)in_sizes; (void)n_in; (void)out_size; (void)ws_size;
    const float* x0   = (const float*)d_in[0];
    const float* x1   = (const float*)d_in[1];
    const float* xib  = (const float*)d_in[2];
    const float* pW0  = (const float*)d_in[3];
    const float* pb0  = (const float*)d_in[4];
    const float* pW1  = (const float*)d_in[5];
    const float* pb1  = (const float*)d_in[6];
    const float* pWib = (const float*)d_in[7];
    const float* pbib = (const float*)d_in[8];
    const float* rw1  = (const float*)d_in[9];
    const float* rb1  = (const float*)d_in[10];
    const float* rg1  = (const float*)d_in[11];
    const float* rbt1 = (const float*)d_in[12];
    const float* rw2  = (const float*)d_in[13];
    const float* rb2  = (const float*)d_in[14];
    const float* rg2  = (const float*)d_in[15];
    const float* rbt2 = (const float*)d_in[16];
    const float* rw3  = (const float*)d_in[17];
    const float* rb3  = (const float*)d_in[18];
    float* out = (float*)d_out;

    char* ws = (char*)d_ws;
    // --- workspace layout (total ~56.1 MB, with aliasing) ---
    unsigned short* Wmt = (unsigned short*)(ws);  // [1536, 2816] bf16
    char* stats = ws + 8650752;
    float* sum1   = (float*)(stats + 0);      // 512 f
    float* sumsq1 = (float*)(stats + 2048);   // 512 f
    float* sum2   = (float*)(stats + 4096);   // 128 f
    float* sumsq2 = (float*)(stats + 4608);   // 128 f
    float* scale1 = (float*)(stats + 5120);
    float* shift1 = (float*)(stats + 7168);
    float* scale2 = (float*)(stats + 9216);
    float* shift2 = (float*)(stats + 9728);
    float* bm0    = (float*)(stats + 10240);
    float* bm1    = (float*)(stats + 16384);
    float* bm2    = (float*)(stats + 22528);
    float* w0p    = (float*)(stats + 28672);
    float* w1p    = (float*)(stats + 61440);
    float* w2p    = (float*)(stats + 94208);
    unsigned short* rw1t = (unsigned short*)(ws + 8781824);   // [512,1024] bf16
    unsigned short* rw2t = (unsigned short*)(ws + 9830400);   // [128,512] bf16 (padded)
    char* R5 = ws + 9961472;
    unsigned short* X0b = (unsigned short*)(R5);              // [8192,1024] bf16
    float* h1           = (float*)(R5 + 16777216);            // [8192,512] f32
    unsigned short* h1n = (unsigned short*)(R5 + 33554432);   // [8192,512] bf16
    float* h2           = (float*)(R5 + 41943040);            // [8192,100] f32
    unsigned short* Xp  = (unsigned short*)(R5);              // [8192,2816] bf16 (aliases all of R5)

    dim3 tblk(32, 8);
    // expert-weight averaging + transpose + bf16 (Wmt k-slices)
    avg_transpose_bf16<<<dim3(32, 48), tblk, 0, stream>>>(pW0, Wmt + 0, 7, 1024, 1536, 1536, 2816, 1.f / 7.f);
    avg_transpose_bf16<<<dim3(24, 48), tblk, 0, stream>>>(pW1, Wmt + 1024, 7, 768, 1536, 1536, 2816, 1.f / 7.f);
    avg_transpose_bf16<<<dim3(32, 48), tblk, 0, stream>>>(pWib, Wmt + 1792, 7, 1024, 1536, 1536, 2816, 1.f / 7.f);
    avg_transpose_bf16<<<dim3(32, 16), tblk, 0, stream>>>(rw1, rw1t, 1, 1024, 512, 512, 1024, 1.f);
    avg_transpose_bf16<<<dim3(16, 4), tblk, 0, stream>>>(rw2, rw2t, 1, 512, 100, 128, 512, 1.f);
    bias_means<<<6, 256, 0, stream>>>(pb0, pb1, pbib, bm0, bm1, bm2);
    pack_bf16<<<8192, 256, 0, stream>>>(x0, X0b, 8192 * 1024 / 4);
    hipMemsetAsync(stats, 0, 5120, stream);

    // router GEMM1: h1 = x0 @ rw1 + rb1
    gemm_bt<0><<<dim3(64, 4), 256, 0, stream>>>(X0b, rw1t, h1, 1024, 512, 512,
                                                rb1, nullptr, nullptr, nullptr,
                                                nullptr, nullptr, nullptr);
    bn_stats<<<64, 256, 0, stream>>>(h1, 512, 128, sum1, sumsq1);
    bn_final<<<2, 256, 0, stream>>>(512, 1.f / 8192.f, sum1, sumsq1, rg1, rbt1, scale1, shift1);
    bn_relu_pack<<<4096, 256, 0, stream>>>(h1, h1n, scale1, shift1, 128, 8192 * 512 / 4);
    // router GEMM2: h2 = h1n @ rw2 + rb2  (N padded to 128)
    gemm_bt<0><<<dim3(64, 1), 256, 0, stream>>>(h1n, rw2t, h2, 512, 100, 100,
                                                rb2, nullptr, nullptr, nullptr,
                                                nullptr, nullptr, nullptr);
    bn_stats<<<64, 256, 0, stream>>>(h2, 100, 128, sum2, sumsq2);
    bn_final<<<1, 128, 0, stream>>>(100, 1.f / 8192.f, sum2, sumsq2, rg2, rbt2, scale2, shift2);
    router_tail<<<32, 256, 0, stream>>>(h2, scale2, shift2, rw3, rb3, w0p, w1p, w2p);

    // pack scaled inputs and run the single big GEMM + bias epilogue
    pack_xp<<<22528, 256, 0, stream>>>(x0, x1, xib, w0p, w1p, w2p, Xp);
    gemm_bt<1><<<dim3(64, 12), 256, 0, stream>>>(Xp, Wmt, out, 2816, 1536, 1536,
                                                 nullptr, w0p, w1p, w2p, bm0, bm1, bm2);
    l2norm_rows<<<2048, 256, 0, stream>>>(out);
}

// Round 2
// 484.471 us; speedup vs baseline: 1.2216x; 1.2216x over previous
//
#include <hip/hip_runtime.h>
#include <stdint.h>

typedef __attribute__((ext_vector_type(8))) short short8;
typedef __attribute__((ext_vector_type(4))) float floatx4;

__device__ inline unsigned short f2bf(float f) {
    unsigned int u = __float_as_uint(f);
    u += 0x7fffu + ((u >> 16) & 1u);   // round-to-nearest-even
    return (unsigned short)(u >> 16);
}

// ---------------------------------------------------------------------------
// Tile worker: average over E experts + transpose + fp32->bf16.
// src[e, k, n] row-major; dst[n, k] bf16, leading dim ldb.
// Rows n in [Nsrc, Ndst) zero-filled (pads rw2 N=100 -> 128).
// ---------------------------------------------------------------------------
__device__ void avg_transpose_tile(const float* __restrict__ src,
                                   unsigned short* __restrict__ dst,
                                   int E, int K, int Nsrc, int Ndst, int ldb,
                                   float scale, int tile_x, int tile_y) {
    __shared__ float tile[32][33];
    const int tid = threadIdx.x;
    const int tx = tid & 31;
    const int ty = tid >> 5;   // 0..7
    const int kb = tile_x * 32;
    const int nb = tile_y * 32;
#pragma unroll
    for (int p = 0; p < 4; ++p) {
        int kl = ty + p * 8;
        int k = kb + kl;
        int n = nb + tx;
        float s = 0.f;
        if (k < K && n < Nsrc) {
            for (int e = 0; e < E; ++e)
                s += src[(size_t)e * K * Nsrc + (size_t)k * Nsrc + n];
        }
        tile[kl][tx] = s * scale;
    }
    __syncthreads();
#pragma unroll
    for (int p = 0; p < 4; ++p) {
        int nl = ty + p * 8;
        int n = nb + nl;
        int k = kb + tx;
        if (n < Ndst && k < K)
            dst[(size_t)n * ldb + k] = f2bf(tile[tx][nl]);
    }
}

// ---------------------------------------------------------------------------
// One fused prep kernel: all weight transforms + bias means + x0 pack + stats
// zeroing.  Task decoded from blockIdx.x.  All subtasks independent.
//   [0,1536)      pW0  avg+T  -> Wmt[:,0:1024]
//   [1536,2688)   pW1  avg+T  -> Wmt[:,1024:1792]
//   [2688,4224)   pWib avg+T  -> Wmt[:,1792:2816]
//   [4224,4736)   rw1  T      -> rw1t
//   [4736,4800)   rw2  T(pad) -> rw2t
//   [4800,4806)   bias means
//   [4806,4807)   zero stats (1280 floats)
//   [4807,6855)   pack x0 -> bf16
// ---------------------------------------------------------------------------
__global__ __launch_bounds__(256) void prep(
    const float* __restrict__ pW0, const float* __restrict__ pW1,
    const float* __restrict__ pWib, const float* __restrict__ rw1,
    const float* __restrict__ rw2, const float* __restrict__ pb0,
    const float* __restrict__ pb1, const float* __restrict__ pbib,
    const float* __restrict__ x0,
    unsigned short* __restrict__ Wmt, unsigned short* __restrict__ rw1t,
    unsigned short* __restrict__ rw2t, float* __restrict__ bm0,
    float* __restrict__ bm1, float* __restrict__ bm2,
    float* __restrict__ stats_zero, unsigned short* __restrict__ X0b) {
    int id = blockIdx.x;
    int tid = threadIdx.x;
    if (id < 1536) {
        avg_transpose_tile(pW0, Wmt + 0, 7, 1024, 1536, 1536, 2816, 1.f / 7.f,
                           id % 32, id / 32);
    } else if (id < 2688) {
        int t = id - 1536;
        avg_transpose_tile(pW1, Wmt + 1024, 7, 768, 1536, 1536, 2816, 1.f / 7.f,
                           t % 24, t / 24);
    } else if (id < 4224) {
        int t = id - 2688;
        avg_transpose_tile(pWib, Wmt + 1792, 7, 1024, 1536, 1536, 2816,
                           1.f / 7.f, t % 32, t / 32);
    } else if (id < 4736) {
        int t = id - 4224;
        avg_transpose_tile(rw1, rw1t, 1, 1024, 512, 512, 1024, 1.f, t % 32,
                           t / 32);
    } else if (id < 4800) {
        int t = id - 4736;
        avg_transpose_tile(rw2, rw2t, 1, 512, 100, 128, 512, 1.f, t % 16,
                           t / 16);
    } else if (id < 4806) {
        int i = (id - 4800) * 256 + tid;
        if (i < 1536) {
            float s0 = 0.f, s1 = 0.f, s2 = 0.f;
            for (int e = 0; e < 7; ++e) {
                s0 += pb0[e * 1536 + i];
                s1 += pb1[e * 1536 + i];
                s2 += pbib[e * 1536 + i];
            }
            const float inv = 1.f / 7.f;
            bm0[i] = s0 * inv; bm1[i] = s1 * inv; bm2[i] = s2 * inv;
        }
    } else if (id < 4807) {
        for (int i = tid; i < 1280; i += 256) stats_zero[i] = 0.f;
    } else {
        int base = (id - 4807) * 1024;  // vec4 index base; 2048 blocks
#pragma unroll
        for (int k = 0; k < 4; ++k) {
            int i = base + k * 256 + tid;
            float4 v = ((const float4*)x0)[i];
            ushort4 o;
            o.x = f2bf(v.x); o.y = f2bf(v.y); o.z = f2bf(v.z); o.w = f2bf(v.w);
            ((ushort4*)X0b)[i] = o;
        }
    }
}

// ---------------------------------------------------------------------------
// bf16 MFMA GEMM, m97 structure: 128x128 tile, BK=32, 4 waves (2x2 of 64x64),
// global_load_lds width 16.  A[M,K] bf16 row-major, Bt[Npad,K] bf16 row-major.
// C fp32 [M, Nreal], leading dim ldc.
// MODE 1: C = A*B + w0[m]*bm0[n] + w1[m]*bm1[n] + w2[m]*bm2[n]
// MODE 2: C = A*B + bias[n], plus per-column atomic sum/sumsq (BN stats)
// Requires: M % 128 == 0, grid.y*128 rows valid in Bt, K % 32 == 0.
// ---------------------------------------------------------------------------
template <int MODE>
__global__ __launch_bounds__(256) void gemm_bt(
    const unsigned short* __restrict__ A, const unsigned short* __restrict__ Bt,
    float* __restrict__ C, int K, int Nreal, int ldc,
    const float* __restrict__ bias, float* __restrict__ sum,
    float* __restrict__ sumsq, const float* __restrict__ w0,
    const float* __restrict__ w1, const float* __restrict__ w2,
    const float* __restrict__ bm0, const float* __restrict__ bm1,
    const float* __restrict__ bm2) {
    __shared__ __align__(16) unsigned short As[128 * 32];
    __shared__ __align__(16) unsigned short Bs[128 * 32];
    const int tid = threadIdx.x;
    const int lane = tid & 63;
    const int wv = tid >> 6;
    const int bm_off = blockIdx.x * 128;
    const int bn_off = blockIdx.y * 128;
    const int wm = (wv & 1) * 64;
    const int wn = (wv >> 1) * 64;
    floatx4 acc[4][4];
#pragma unroll
    for (int i = 0; i < 4; ++i)
#pragma unroll
        for (int j = 0; j < 4; ++j) acc[i][j] = (floatx4){0.f, 0.f, 0.f, 0.f};

    const int quad = lane >> 4;
    const int lrow = lane & 15;
    const int srow = lane >> 2;        // staging: row within 16-row chunk
    const int scol = (lane & 3) * 8;   // staging: elem offset (8 bf16 = 16B)

    const unsigned short* Ag = A + (size_t)bm_off * K;
    const unsigned short* Bg = Bt + (size_t)bn_off * K;

    for (int k0 = 0; k0 < K; k0 += 32) {
#pragma unroll
        for (int r = 0; r < 2; ++r) {
            int chunk = r * 4 + wv;  // 0..7 -> 16-row chunk
            {
                const unsigned short* gp =
                    Ag + (size_t)(chunk * 16 + srow) * K + (k0 + scol);
                __builtin_amdgcn_global_load_lds(
                    (const __attribute__((address_space(1))) void*)gp,
                    (__attribute__((address_space(3))) void*)(As + chunk * 512),
                    16, 0, 0);
            }
            {
                const unsigned short* gp =
                    Bg + (size_t)(chunk * 16 + srow) * K + (k0 + scol);
                __builtin_amdgcn_global_load_lds(
                    (const __attribute__((address_space(1))) void*)gp,
                    (__attribute__((address_space(3))) void*)(Bs + chunk * 512),
                    16, 0, 0);
            }
        }
        __syncthreads();
        short8 af[4], bfr[4];
#pragma unroll
        for (int i = 0; i < 4; ++i)
            af[i] = *(const short8*)(As + (wm + i * 16 + lrow) * 32 + quad * 8);
#pragma unroll
        for (int j = 0; j < 4; ++j)
            bfr[j] = *(const short8*)(Bs + (wn + j * 16 + lrow) * 32 + quad * 8);
#pragma unroll
        for (int i = 0; i < 4; ++i)
#pragma unroll
            for (int j = 0; j < 4; ++j)
                acc[i][j] = __builtin_amdgcn_mfma_f32_16x16x32_bf16(
                    af[i], bfr[j], acc[i][j], 0, 0, 0);
        __syncthreads();
    }

    if (MODE == 1) {
#pragma unroll
        for (int i = 0; i < 4; ++i) {
#pragma unroll
            for (int r = 0; r < 4; ++r) {
                int m = bm_off + wm + i * 16 + quad * 4 + r;
                float wb0 = w0[m], wb1 = w1[m], wb2 = w2[m];
#pragma unroll
                for (int j = 0; j < 4; ++j) {
                    int n = bn_off + wn + j * 16 + lrow;
                    float v = acc[i][j][r] + wb0 * bm0[n] + wb1 * bm1[n] +
                              wb2 * bm2[n];
                    C[(size_t)m * ldc + n] = v;
                }
            }
        }
    } else {  // MODE 2
#pragma unroll
        for (int j = 0; j < 4; ++j) {
            int n = bn_off + wn + j * 16 + lrow;
            bool nok = (n < Nreal);
            float bv = nok ? bias[n] : 0.f;
            float s = 0.f, ss = 0.f;
#pragma unroll
            for (int i = 0; i < 4; ++i) {
#pragma unroll
                for (int r = 0; r < 4; ++r) {
                    float v = acc[i][j][r] + bv;
                    int m = bm_off + wm + i * 16 + quad * 4 + r;
                    if (nok) C[(size_t)m * ldc + n] = v;
                    s += v; ss += v * v;
                }
            }
            s += __shfl_xor(s, 16); s += __shfl_xor(s, 32);
            ss += __shfl_xor(ss, 16); ss += __shfl_xor(ss, 32);
            if (quad == 0 && nok) {
                atomicAdd(&sum[n], s);
                atomicAdd(&sumsq[n], ss);
            }
        }
    }
}

// BN1 final (from sums, in LDS) + relu + bf16 pack.  h1 [8192,512].
__global__ __launch_bounds__(256) void bn_relu_pack(
    const float* __restrict__ h, unsigned short* __restrict__ out,
    const float* __restrict__ sum, const float* __restrict__ sumsq,
    const float* __restrict__ g, const float* __restrict__ b) {
    __shared__ float sc[512], sh[512];
    const float invB = 1.f / 8192.f;
    for (int c = threadIdx.x; c < 512; c += 256) {
        float m = sum[c] * invB;
        float v = sumsq[c] * invB - m * m;
        float s = g[c] * rsqrtf(v + 1e-5f);
        sc[c] = s;
        sh[c] = b[c] - m * s;
    }
    __syncthreads();
    int base = blockIdx.x * 4096;  // vec4 units; 256 blocks
#pragma unroll
    for (int k = 0; k < 16; ++k) {
        int i = base + k * 256 + threadIdx.x;
        int c4 = (i & 127) * 4;
        float4 v = ((const float4*)h)[i];
        ushort4 o;
        o.x = f2bf(fmaxf(v.x * sc[c4 + 0] + sh[c4 + 0], 0.f));
        o.y = f2bf(fmaxf(v.y * sc[c4 + 1] + sh[c4 + 1], 0.f));
        o.z = f2bf(fmaxf(v.z * sc[c4 + 2] + sh[c4 + 2], 0.f));
        o.w = f2bf(fmaxf(v.w * sc[c4 + 3] + sh[c4 + 3], 0.f));
        ((ushort4*)out)[i] = o;
    }
}

// BN2 final (in LDS) + tanh + [100x3] GEMM + sigmoid + softmax.
__global__ __launch_bounds__(128) void router_tail(
    const float* __restrict__ h2, const float* __restrict__ sum,
    const float* __restrict__ sumsq, const float* __restrict__ g,
    const float* __restrict__ b, const float* __restrict__ rw3,
    const float* __restrict__ rb3, float* __restrict__ w0,
    float* __restrict__ w1, float* __restrict__ w2) {
    __shared__ float sc[100], sh[100], w3[300], b3[3];
    int tid = threadIdx.x;
    const float invB = 1.f / 8192.f;
    if (tid < 100) {
        float m = sum[tid] * invB;
        float v = sumsq[tid] * invB - m * m;
        float s = g[tid] * rsqrtf(v + 1e-5f);
        sc[tid] = s;
        sh[tid] = b[tid] - m * s;
    }
    for (int i = tid; i < 300; i += 128) w3[i] = rw3[i];
    if (tid < 3) b3[tid] = rb3[tid];
    __syncthreads();
    int bi = blockIdx.x * 128 + tid;
    float l0 = b3[0], l1 = b3[1], l2 = b3[2];
    const float* hr = h2 + (size_t)bi * 100;
    for (int k = 0; k < 100; ++k) {
        float t = tanhf(hr[k] * sc[k] + sh[k]);
        l0 += t * w3[k * 3 + 0];
        l1 += t * w3[k * 3 + 1];
        l2 += t * w3[k * 3 + 2];
    }
    l0 = 1.f / (1.f + expf(-l0));
    l1 = 1.f / (1.f + expf(-l1));
    l2 = 1.f / (1.f + expf(-l2));
    float mx = fmaxf(l0, fmaxf(l1, l2));
    float e0 = expf(l0 - mx), e1 = expf(l1 - mx), e2 = expf(l2 - mx);
    float inv = 1.f / (e0 + e1 + e2);
    w0[bi] = e0 * inv; w1[bi] = e1 * inv; w2[bi] = e2 * inv;
}

// X'[b] = [w0[b]*x0[b] | w1[b]*x1[b] | w2[b]*x_ib[b]] as bf16, [8192, 2816]
__global__ __launch_bounds__(256) void pack_xp(
    const float* __restrict__ x0, const float* __restrict__ x1,
    const float* __restrict__ xib, const float* __restrict__ w0,
    const float* __restrict__ w1, const float* __restrict__ w2,
    unsigned short* __restrict__ Xp) {
    int i = blockIdx.x * blockDim.x + threadIdx.x;  // 8192*704 vec4 groups
    if (i >= 8192 * 704) return;
    int b = i / 704;
    int g = i % 704;
    const float* src;
    float w;
    int col;
    if (g < 256)      { src = x0 + (size_t)b * 1024 + g * 4;          w = w0[b]; col = g * 4; }
    else if (g < 448) { src = x1 + (size_t)b * 768 + (g - 256) * 4;   w = w1[b]; col = 1024 + (g - 256) * 4; }
    else              { src = xib + (size_t)b * 1024 + (g - 448) * 4; w = w2[b]; col = 1792 + (g - 448) * 4; }
    float4 v = *(const float4*)src;
    ushort4 o;
    o.x = f2bf(v.x * w); o.y = f2bf(v.y * w);
    o.z = f2bf(v.z * w); o.w = f2bf(v.w * w);
    *(ushort4*)(Xp + (size_t)b * 2816 + col) = o;
}

// per-row L2 normalization in place, one wave per row (1536 cols)
__global__ __launch_bounds__(256) void l2norm_rows(float* __restrict__ out) {
    int wv = threadIdx.x >> 6;
    int lane = threadIdx.x & 63;
    int row = blockIdx.x * 4 + wv;
    float4* rp = (float4*)(out + (size_t)row * 1536);
    float4 v[6];
    float ss = 0.f;
#pragma unroll
    for (int t = 0; t < 6; ++t) {
        v[t] = rp[lane + t * 64];
        ss += v[t].x * v[t].x + v[t].y * v[t].y + v[t].z * v[t].z + v[t].w * v[t].w;
    }
#pragma unroll
    for (int o = 32; o > 0; o >>= 1) ss += __shfl_xor(ss, o);
    float inv = 1.f / fmaxf(sqrtf(ss), 1e-12f);
#pragma unroll
    for (int t = 0; t < 6; ++t) {
        v[t].x *= inv; v[t].y *= inv; v[t].z *= inv; v[t].w *= inv;
        rp[lane + t * 64] = v[t];
    }
}

extern "C" void kernel_launch(void* const* d_in, const int* in_sizes, int n_in,
                              void* d_out, int out_size, void* d_ws,
                              size_t ws_size, hipStream_t stream) {
    (void)in_sizes; (void)n_in; (void)out_size; (void)ws_size;
    const float* x0   = (const float*)d_in[0];
    const float* x1   = (const float*)d_in[1];
    const float* xib  = (const float*)d_in[2];
    const float* pW0  = (const float*)d_in[3];
    const float* pb0  = (const float*)d_in[4];
    const float* pW1  = (const float*)d_in[5];
    const float* pb1  = (const float*)d_in[6];
    const float* pWib = (const float*)d_in[7];
    const float* pbib = (const float*)d_in[8];
    const float* rw1  = (const float*)d_in[9];
    const float* rb1  = (const float*)d_in[10];
    const float* rg1  = (const float*)d_in[11];
    const float* rbt1 = (const float*)d_in[12];
    const float* rw2  = (const float*)d_in[13];
    const float* rb2  = (const float*)d_in[14];
    const float* rg2  = (const float*)d_in[15];
    const float* rbt2 = (const float*)d_in[16];
    const float* rw3  = (const float*)d_in[17];
    const float* rb3  = (const float*)d_in[18];
    float* out = (float*)d_out;

    char* ws = (char*)d_ws;
    // --- workspace layout (~56 MB, with aliasing) ---
    unsigned short* Wmt = (unsigned short*)(ws);  // [1536, 2816] bf16
    char* stats = ws + 8650752;
    float* sum1   = (float*)(stats + 0);      // 512 f
    float* sumsq1 = (float*)(stats + 2048);   // 512 f
    float* sum2   = (float*)(stats + 4096);   // 128 f
    float* sumsq2 = (float*)(stats + 4608);   // 128 f  (zero region = 1280 f)
    float* bm0    = (float*)(stats + 10240);
    float* bm1    = (float*)(stats + 16384);
    float* bm2    = (float*)(stats + 22528);
    float* w0p    = (float*)(stats + 28672);
    float* w1p    = (float*)(stats + 61440);
    float* w2p    = (float*)(stats + 94208);
    unsigned short* rw1t = (unsigned short*)(ws + 8781824);   // [512,1024] bf16
    unsigned short* rw2t = (unsigned short*)(ws + 9830400);   // [128,512] bf16 (padded)
    char* R5 = ws + 9961472;
    unsigned short* X0b = (unsigned short*)(R5);              // [8192,1024] bf16
    float* h1           = (float*)(R5 + 16777216);            // [8192,512] f32
    unsigned short* h1n = (unsigned short*)(R5 + 33554432);   // [8192,512] bf16
    float* h2           = (float*)(R5 + 41943040);            // [8192,100] f32
    unsigned short* Xp  = (unsigned short*)(R5);              // [8192,2816] bf16 (aliases X0b region)

    // 1. fused prep: weight transforms + bias means + x0 pack + stats zero
    prep<<<6855, 256, 0, stream>>>(pW0, pW1, pWib, rw1, rw2, pb0, pb1, pbib, x0,
                                   Wmt, rw1t, rw2t, bm0, bm1, bm2,
                                   (float*)stats, X0b);
    // 2. router GEMM1: h1 = x0 @ rw1 + rb1, with fused BN stats
    gemm_bt<2><<<dim3(64, 4), 256, 0, stream>>>(
        X0b, rw1t, h1, 1024, 512, 512, rb1, sum1, sumsq1,
        nullptr, nullptr, nullptr, nullptr, nullptr, nullptr);
    // 3. BN1 apply + relu + bf16 pack
    bn_relu_pack<<<256, 256, 0, stream>>>(h1, h1n, sum1, sumsq1, rg1, rbt1);
    // 4. router GEMM2: h2 = h1n @ rw2 + rb2 (N padded to 128), fused BN stats
    gemm_bt<2><<<dim3(64, 1), 256, 0, stream>>>(
        h1n, rw2t, h2, 512, 100, 100, rb2, sum2, sumsq2,
        nullptr, nullptr, nullptr, nullptr, nullptr, nullptr);
    // 5. BN2 + tanh + small GEMM + sigmoid + softmax -> router weights
    router_tail<<<64, 128, 0, stream>>>(h2, sum2, sumsq2, rg2, rbt2, rw3, rb3,
                                        w0p, w1p, w2p);
    // 6. pack scaled inputs
    pack_xp<<<22528, 256, 0, stream>>>(x0, x1, xib, w0p, w1p, w2p, Xp);
    // 7. big GEMM + weighted-bias epilogue
    gemm_bt<1><<<dim3(64, 12), 256, 0, stream>>>(
        Xp, Wmt, out, 2816, 1536, 1536, nullptr, nullptr, nullptr,
        w0p, w1p, w2p, bm0, bm1, bm2);
    // 8. per-row L2 normalize
    l2norm_rows<<<2048, 256, 0, stream>>>(out);
}